// Round 9
// baseline (378.429 us; speedup 1.0000x reference)
//
#include <hip/hip_runtime.h>
#include <math.h>

#define Bdim 2
#define Edim 16
#define Udim 8
#define Ndim 400
#define Ddim 24

// Workspace layout (float offsets)
#define WS_S     0              // B*D*D  = 1152
#define WS_INP   1152           // B*N*D  = 19200
#define WS_LOGK  20352          // B*E*N  = 12800
#define WS_PM    33152          // B*E    = 32
#define WS_V     33184          // B*D*E  = 768
#define WS_SBLB  33952          // B*E*E  = 512
#define WS_TR    34464          // B*E    = 32
#define WS_SCALE 34496          // B*E*E  = 512
// total 35008 floats = 140032 bytes

// ---------------------------------------------------------------------------
// Kernel A: per (b,e): S, Bmat^-1 (Gauss-Jordan), c, lb, pred_mean, V, logk
// ---------------------------------------------------------------------------
__global__ __launch_bounds__(256) void prep_kernel(
    const float* __restrict__ m_x, const float* __restrict__ s_x,
    const float* __restrict__ m_u, const float* __restrict__ s_u,
    const float* __restrict__ c_xu, const float* __restrict__ X_train,
    const float* __restrict__ lengthscales, const float* __restrict__ variances,
    const float* __restrict__ beta, float* __restrict__ ws)
{
    const int b = blockIdx.x / Edim;
    const int e = blockIdx.x % Edim;
    const int t = threadIdx.x;
    const int NT = 256;

    __shared__ float sS[Ddim][Ddim];
    __shared__ float sm[Ddim];
    __shared__ float siL[Ddim], siLsq[Ddim];
    __shared__ float aug[Ddim][2*Ddim];
    __shared__ float fac[Ddim];
    __shared__ float slogdet;
    __shared__ float scv;
    __shared__ float sV[Ddim];
    __shared__ float s_lb;

    if (t < Edim) sm[t] = m_x[b*Edim + t];
    else if (t < Ddim) sm[t] = m_u[b*Udim + (t - Edim)];
    if (t < Ddim) {
        float L = lengthscales[e*Ddim + t];
        siL[t] = 1.f / L;
        siLsq[t] = 1.f / (L*L);
        sV[t] = 0.f;
    }
    if (t == 0) { slogdet = 0.f; s_lb = 0.f; }
    __syncthreads();

    // Build S = [[s_x, s_x@c_xu],[(s_x@c_xu)^T, s_u]]
    for (int idx = t; idx < Ddim*Ddim; idx += NT) {
        int i = idx / Ddim, j = idx % Ddim;
        float val;
        if (i < Edim && j < Edim) {
            val = s_x[(b*Edim + i)*Edim + j];
        } else if (i >= Edim && j >= Edim) {
            val = s_u[(b*Udim + (i-Edim))*Udim + (j-Edim)];
        } else {
            int r  = (i < Edim) ? i : j;            // row into s_x
            int cc = (i < Edim) ? (j - Edim) : (i - Edim); // col into c_xu
            float acc = 0.f;
            for (int k = 0; k < Edim; k++)
                acc += s_x[(b*Edim + r)*Edim + k] * c_xu[(b*Edim + k)*Udim + cc];
            val = acc;
        }
        sS[i][j] = val;
        if (e == 0) ws[WS_S + b*Ddim*Ddim + idx] = val;
    }
    __syncthreads();

    // Bmat = diag(iL) S diag(iL) + I, augmented with I
    for (int idx = t; idx < Ddim*2*Ddim; idx += NT) {
        int i = idx / (2*Ddim), j = idx % (2*Ddim);
        float v;
        if (j < Ddim) v = siL[i]*sS[i][j]*siL[j] + ((i==j) ? 1.f : 0.f);
        else          v = ((j - Ddim) == i) ? 1.f : 0.f;
        aug[i][j] = v;
    }
    __syncthreads();

    // Gauss-Jordan (diagonally dominant: no pivoting)
    for (int k = 0; k < Ddim; k++) {
        float piv = aug[k][k];
        __syncthreads();
        float ipv = 1.f / piv;
        if (t < 2*Ddim) aug[k][t] *= ipv;
        if (t < Ddim) fac[t] = aug[t][k];   // t==k is same-thread after its write
        if (t == 0) slogdet += logf(fabsf(piv));
        __syncthreads();
        for (int idx = t; idx < Ddim*2*Ddim; idx += NT) {
            int i = idx / (2*Ddim), j = idx % (2*Ddim);
            if (i != k) aug[i][j] -= fac[i]*aug[k][j];
        }
        __syncthreads();
    }

    if (t == 0) scv = variances[e] * __expf(-0.5f * slogdet);
    __syncthreads();
    const float cval = scv;
    const float logvar = logf(variances[e]);

    float accV[Ddim];
    #pragma unroll
    for (int d = 0; d < Ddim; d++) accV[d] = 0.f;
    float acc_lb = 0.f;

    for (int n = t; n < Ndim; n += NT) {
        float ipv[Ddim], q[Ddim];
        #pragma unroll
        for (int d = 0; d < Ddim; d++) {
            float x = X_train[n*Ddim + d] - sm[d];
            ipv[d] = x;
            q[d] = x * siL[d];
        }
        float tv[Ddim];
        #pragma unroll
        for (int i = 0; i < Ddim; i++) {
            float acc = 0.f;
            #pragma unroll
            for (int j = 0; j < Ddim; j++) acc = fmaf(aug[i][Ddim + j], q[j], acc);
            tv[i] = acc;
        }
        float qt = 0.f, sq2 = 0.f;
        #pragma unroll
        for (int d = 0; d < Ddim; d++) {
            qt  = fmaf(q[d], tv[d], qt);
            sq2 = fmaf(ipv[d]*ipv[d], siLsq[d], sq2);
        }
        float lb = __expf(-0.5f*qt) * beta[e*Ndim + n];
        acc_lb += lb;
        #pragma unroll
        for (int d = 0; d < Ddim; d++) accV[d] = fmaf(tv[d]*siL[d], lb, accV[d]);
        ws[WS_LOGK + (b*Edim + e)*Ndim + n] = logvar - 0.5f*sq2;
        if (e == 0) {
            #pragma unroll
            for (int d = 0; d < Ddim; d++) ws[WS_INP + (b*Ndim + n)*Ddim + d] = ipv[d];
        }
    }
    atomicAdd(&s_lb, acc_lb);
    #pragma unroll
    for (int d = 0; d < Ddim; d++) atomicAdd(&sV[d], accV[d]);
    __syncthreads();
    if (t == 0) ws[WS_PM + b*Edim + e] = cval * s_lb;
    if (t < Ddim) ws[WS_V + (b*Ddim + t)*Edim + e] = cval * sV[t];
}

// ---------------------------------------------------------------------------
// Kernel B: per (b,a,c): Q2 = 0.5 R^-1 S, scale; then streamed
//           S_bLb = sum_ij u_i v_j exp(cross_ij)  (+ trace for a==c)
// Byte-identical to the round-1 (70us) version EXCEPT __launch_bounds__(512,4):
// caps VGPR at 128 so 2 blocks/CU co-reside (r1 ran 1 block/CU, occ 24.8%),
// doubling waves/SIMD for latency hiding.
// ---------------------------------------------------------------------------
__global__ __launch_bounds__(512, 4) void main_kernel(
    const float* __restrict__ lengthscales, const float* __restrict__ beta,
    const float* __restrict__ inv_K, float* __restrict__ ws)
{
    const int bid = blockIdx.x;
    const int b = bid / (Edim*Edim);
    const int a = (bid / Edim) % Edim;
    const int c = bid % Edim;
    const int t = threadIdx.x;
    const int NT = 512;
    const bool diag = (a == c);

    __shared__ float sS[Ddim][Ddim];
    __shared__ float sQ2[Ddim][Ddim];
    __shared__ float aug[Ddim][2*Ddim];
    __shared__ float fac[Ddim];
    __shared__ float sLamA[Ddim], sLamC[Ddim];
    __shared__ float yc[Ndim][28];          // padded: stride 112B, 16B-aligned rows
    __shared__ float su[Ndim], sv[Ndim], sp[Ndim], sq_[Ndim];
    __shared__ float slogdet, redS, redT;

    if (t < Ddim) {
        float La = lengthscales[a*Ddim + t];
        float Lc = lengthscales[c*Ddim + t];
        sLamA[t] = 1.f/(La*La);
        sLamC[t] = 1.f/(Lc*Lc);
    }
    if (t == 0) { slogdet = 0.f; redS = 0.f; redT = 0.f; }
    for (int idx = t; idx < Ddim*Ddim; idx += NT)
        sS[idx/Ddim][idx%Ddim] = ws[WS_S + b*Ddim*Ddim + idx];
    __syncthreads();

    // R = S*diag(LamA+LamC) + I, RHS = S
    for (int idx = t; idx < Ddim*2*Ddim; idx += NT) {
        int i = idx/(2*Ddim), j = idx%(2*Ddim);
        float v;
        if (j < Ddim) v = sS[i][j]*(sLamA[j]+sLamC[j]) + ((i==j) ? 1.f : 0.f);
        else          v = sS[i][j-Ddim];
        aug[i][j] = v;
    }
    __syncthreads();
    for (int k = 0; k < Ddim; k++) {
        float piv = aug[k][k];
        __syncthreads();
        float ipv = 1.f/piv;
        if (t < 2*Ddim) aug[k][t] *= ipv;
        if (t < Ddim) fac[t] = aug[t][k];
        if (t == 0) slogdet += logf(fabsf(piv));
        __syncthreads();
        for (int idx = t; idx < Ddim*2*Ddim; idx += NT) {
            int i = idx/(2*Ddim), j = idx%(2*Ddim);
            if (i != k) aug[i][j] -= fac[i]*aug[k][j];
        }
        __syncthreads();
    }
    for (int idx = t; idx < Ddim*Ddim; idx += NT) {
        int i = idx/Ddim, j = idx%Ddim;
        sQ2[i][j] = 0.5f*aug[i][Ddim + j];
    }
    if (t == 0) ws[WS_SCALE + bid] = __expf(-0.5f*slogdet);
    __syncthreads();

    // phase 1: per training point n: Yc = Q2 z_c, Xs, X2s, u, v, p, q
    if (t < Ndim) {
        int n = t;
        float zav[Ddim], zcv[Ddim];
        #pragma unroll
        for (int d = 0; d < Ddim; d++) {
            float x = ws[WS_INP + (b*Ndim + n)*Ddim + d];
            zav[d] = x * sLamA[d];
            zcv[d] = x * sLamC[d];
        }
        float xs = 0.f, x2s = 0.f;
        #pragma unroll
        for (int i = 0; i < Ddim; i++) {
            float ya = 0.f, ycv = 0.f;
            #pragma unroll
            for (int j = 0; j < Ddim; j++) {
                ya  = fmaf(sQ2[i][j], zav[j], ya);
                ycv = fmaf(sQ2[i][j], zcv[j], ycv);
            }
            xs  = fmaf(zav[i], ya, xs);
            x2s = fmaf(zcv[i], ycv, x2s);
            yc[n][i] = ycv;
        }
        float lka = ws[WS_LOGK + (b*Edim + a)*Ndim + n];
        float lkc = ws[WS_LOGK + (b*Edim + c)*Ndim + n];
        float pa = __expf(lka + xs);
        float qc = __expf(lkc + x2s);
        sp[n] = pa; sq_[n] = qc;
        su[n] = beta[a*Ndim + n]*pa;
        sv[n] = beta[c*Ndim + n]*qc;
    }
    __syncthreads();

    // phase 2: 400x400 exp-dot streaming contraction; threads as 32(i) x 16(j)
    const int tx = t & 15, ty = t >> 4;
    float accS = 0.f, accT = 0.f;
    for (int i0 = 0; i0 < Ndim; i0 += 32) {
        int i = i0 + ty;
        bool iv = (i < Ndim);
        int isafe = iv ? i : 0;
        float zr[Ddim];
        #pragma unroll
        for (int d = 0; d < Ddim; d++)
            zr[d] = ws[WS_INP + (b*Ndim + isafe)*Ddim + d] * sLamA[d];
        float ui = iv ? su[i] : 0.f;
        float pi = (iv && diag) ? sp[i] : 0.f;
        const float* kr = &inv_K[((size_t)a*Ndim + isafe)*Ndim];
        for (int j0 = 0; j0 < Ndim; j0 += 16) {
            int j = j0 + tx;
            float dt = 0.f;
            #pragma unroll
            for (int d = 0; d < Ddim; d++) dt = fmaf(zr[d], yc[j][d], dt);
            float ex = __expf(2.f*dt);
            accS = fmaf(ui*sv[j], ex, accS);
            if (diag) accT = fmaf(pi*sq_[j]*kr[j], ex, accT);
        }
    }
    atomicAdd(&redS, accS);
    if (diag) atomicAdd(&redT, accT);
    __syncthreads();
    if (t == 0) {
        ws[WS_SBLB + bid] = redS;
        if (diag) ws[WS_TR + b*Edim + a] = redT;
    }
}

// ---------------------------------------------------------------------------
// Kernel C: assemble next_mean / next_var
// ---------------------------------------------------------------------------
__global__ __launch_bounds__(256) void final_kernel(
    const float* __restrict__ m_x, const float* __restrict__ s_x,
    const float* __restrict__ variances, const float* __restrict__ ws,
    float* __restrict__ out)
{
    const int b = blockIdx.x;
    const int t = threadIdx.x;
    if (t < Edim) out[b*Edim + t] = m_x[b*Edim + t] + ws[WS_PM + b*Edim + t];
    const int i = t >> 4, j = t & 15;
    float pmi = ws[WS_PM + b*Edim + i], pmj = ws[WS_PM + b*Edim + j];
    float cxij = 0.f, cxji = 0.f;
    #pragma unroll
    for (int d = 0; d < Ddim; d++) {
        cxij += ws[WS_S + b*Ddim*Ddim + i*Ddim + d]*ws[WS_V + (b*Ddim + d)*Edim + j];
        cxji += ws[WS_S + b*Ddim*Ddim + j*Ddim + d]*ws[WS_V + (b*Ddim + d)*Edim + i];
    }
    float sb  = ws[WS_SBLB + (b*Edim + i)*Edim + j];
    float scl = ws[WS_SCALE + (b*Edim + i)*Edim + j];
    float sd = sb;
    if (i == j) sd -= ws[WS_TR + b*Edim + i];
    sd = sd*scl + ((i==j) ? variances[i] : 0.f) - pmi*pmj;
    out[Bdim*Edim + (b*Edim + i)*Edim + j] = s_x[(b*Edim + i)*Edim + j] + sd + cxij + cxji;
}

extern "C" void kernel_launch(void* const* d_in, const int* in_sizes, int n_in,
                              void* d_out, int out_size, void* d_ws, size_t ws_size,
                              hipStream_t stream) {
    const float* m_x     = (const float*)d_in[0];
    const float* s_x     = (const float*)d_in[1];
    const float* m_u     = (const float*)d_in[2];
    const float* s_u     = (const float*)d_in[3];
    const float* c_xu    = (const float*)d_in[4];
    const float* X_train = (const float*)d_in[5];
    const float* ls      = (const float*)d_in[6];
    const float* var     = (const float*)d_in[7];
    // d_in[8] = noises, unused in moment matching
    const float* inv_K   = (const float*)d_in[9];
    const float* beta    = (const float*)d_in[10];
    float* ws  = (float*)d_ws;
    float* out = (float*)d_out;

    hipLaunchKernelGGL(prep_kernel, dim3(Bdim*Edim), dim3(256), 0, stream,
        m_x, s_x, m_u, s_u, c_xu, X_train, ls, var, beta, ws);
    hipLaunchKernelGGL(main_kernel, dim3(Bdim*Edim*Edim), dim3(512), 0, stream,
        ls, beta, inv_K, ws);
    hipLaunchKernelGGL(final_kernel, dim3(Bdim), dim3(256), 0, stream,
        m_x, s_x, var, ws, out);
}

// Round 16
// 311.490 us; speedup vs baseline: 1.2149x; 1.2149x over previous
//
#include <hip/hip_runtime.h>
#include <math.h>

#define Bdim 2
#define Edim 16
#define Udim 8
#define Ndim 400
#define Ddim 24
#define NPAIR 136           // Edim*(Edim+1)/2, pairs a<=c

// Workspace layout (float offsets)
#define WS_S     0              // B*D*D  = 1152
#define WS_INP   1152           // B*N*D  = 19200
#define WS_LOGK  20352          // B*E*N  = 12800
#define WS_PM    33152          // B*E    = 32
#define WS_V     33184          // B*D*E  = 768
#define WS_SBLB  33952          // B*E*E  = 512 (canonical a<=c slots)
#define WS_TR    34464          // B*E    = 32   (contiguous after SBLB: memset both)
#define WS_SCALE 34496          // B*E*E  = 512

// ---------------------------------------------------------------------------
// Kernel A: per (b,e): S, Bmat^-1 (Gauss-Jordan), c, lb, pred_mean, V, logk
// ---------------------------------------------------------------------------
__global__ __launch_bounds__(256) void prep_kernel(
    const float* __restrict__ m_x, const float* __restrict__ s_x,
    const float* __restrict__ m_u, const float* __restrict__ s_u,
    const float* __restrict__ c_xu, const float* __restrict__ X_train,
    const float* __restrict__ lengthscales, const float* __restrict__ variances,
    const float* __restrict__ beta, float* __restrict__ ws)
{
    const int b = blockIdx.x / Edim;
    const int e = blockIdx.x % Edim;
    const int t = threadIdx.x;
    const int NT = 256;

    __shared__ float sS[Ddim][Ddim];
    __shared__ float sm[Ddim];
    __shared__ float siL[Ddim], siLsq[Ddim];
    __shared__ float aug[Ddim][2*Ddim];
    __shared__ float fac[Ddim];
    __shared__ float slogdet;
    __shared__ float scv;
    __shared__ float sV[Ddim];
    __shared__ float s_lb;

    if (t < Edim) sm[t] = m_x[b*Edim + t];
    else if (t < Ddim) sm[t] = m_u[b*Udim + (t - Edim)];
    if (t < Ddim) {
        float L = lengthscales[e*Ddim + t];
        siL[t] = 1.f / L;
        siLsq[t] = 1.f / (L*L);
        sV[t] = 0.f;
    }
    if (t == 0) { slogdet = 0.f; s_lb = 0.f; }
    __syncthreads();

    // Build S = [[s_x, s_x@c_xu],[(s_x@c_xu)^T, s_u]]
    for (int idx = t; idx < Ddim*Ddim; idx += NT) {
        int i = idx / Ddim, j = idx % Ddim;
        float val;
        if (i < Edim && j < Edim) {
            val = s_x[(b*Edim + i)*Edim + j];
        } else if (i >= Edim && j >= Edim) {
            val = s_u[(b*Udim + (i-Edim))*Udim + (j-Edim)];
        } else {
            int r  = (i < Edim) ? i : j;
            int cc = (i < Edim) ? (j - Edim) : (i - Edim);
            float acc = 0.f;
            for (int k = 0; k < Edim; k++)
                acc += s_x[(b*Edim + r)*Edim + k] * c_xu[(b*Edim + k)*Udim + cc];
            val = acc;
        }
        sS[i][j] = val;
        if (e == 0) ws[WS_S + b*Ddim*Ddim + idx] = val;
    }
    __syncthreads();

    // Bmat = diag(iL) S diag(iL) + I, augmented with I
    for (int idx = t; idx < Ddim*2*Ddim; idx += NT) {
        int i = idx / (2*Ddim), j = idx % (2*Ddim);
        float v;
        if (j < Ddim) v = siL[i]*sS[i][j]*siL[j] + ((i==j) ? 1.f : 0.f);
        else          v = ((j - Ddim) == i) ? 1.f : 0.f;
        aug[i][j] = v;
    }
    __syncthreads();

    // Gauss-Jordan (diagonally dominant: no pivoting)
    for (int k = 0; k < Ddim; k++) {
        float piv = aug[k][k];
        __syncthreads();
        float ipv = 1.f / piv;
        if (t < 2*Ddim) aug[k][t] *= ipv;
        if (t < Ddim) fac[t] = aug[t][k];
        if (t == 0) slogdet += logf(fabsf(piv));
        __syncthreads();
        for (int idx = t; idx < Ddim*2*Ddim; idx += NT) {
            int i = idx / (2*Ddim), j = idx % (2*Ddim);
            if (i != k) aug[i][j] -= fac[i]*aug[k][j];
        }
        __syncthreads();
    }

    if (t == 0) scv = variances[e] * __expf(-0.5f * slogdet);
    __syncthreads();
    const float cval = scv;
    const float logvar = logf(variances[e]);

    float accV[Ddim];
    #pragma unroll
    for (int d = 0; d < Ddim; d++) accV[d] = 0.f;
    float acc_lb = 0.f;

    for (int n = t; n < Ndim; n += NT) {
        float ipv[Ddim], q[Ddim];
        #pragma unroll
        for (int d = 0; d < Ddim; d++) {
            float x = X_train[n*Ddim + d] - sm[d];
            ipv[d] = x;
            q[d] = x * siL[d];
        }
        float tv[Ddim];
        #pragma unroll
        for (int i = 0; i < Ddim; i++) {
            float acc = 0.f;
            #pragma unroll
            for (int j = 0; j < Ddim; j++) acc = fmaf(aug[i][Ddim + j], q[j], acc);
            tv[i] = acc;
        }
        float qt = 0.f, sq2 = 0.f;
        #pragma unroll
        for (int d = 0; d < Ddim; d++) {
            qt  = fmaf(q[d], tv[d], qt);
            sq2 = fmaf(ipv[d]*ipv[d], siLsq[d], sq2);
        }
        float lb = __expf(-0.5f*qt) * beta[e*Ndim + n];
        acc_lb += lb;
        #pragma unroll
        for (int d = 0; d < Ddim; d++) accV[d] = fmaf(tv[d]*siL[d], lb, accV[d]);
        ws[WS_LOGK + (b*Edim + e)*Ndim + n] = logvar - 0.5f*sq2;
        if (e == 0) {
            #pragma unroll
            for (int d = 0; d < Ddim; d++) ws[WS_INP + (b*Ndim + n)*Ddim + d] = ipv[d];
        }
    }
    atomicAdd(&s_lb, acc_lb);
    #pragma unroll
    for (int d = 0; d < Ddim; d++) atomicAdd(&sV[d], accV[d]);
    __syncthreads();
    if (t == 0) ws[WS_PM + b*Edim + e] = cval * s_lb;
    if (t < Ddim) ws[WS_V + (b*Ddim + t)*Edim + e] = cval * sV[t];
}

// ---------------------------------------------------------------------------
// Phase-2 body: r7 structure + 2 i-rows per thread sharing each yc[j] read
// (halves LDS traffic — the measured bottleneck). All loop bounds are
// compile-time constants. Block IH of {0,1,2} covers i-blocks:
//   IH=0: [0,64) [192,256) [384,400)   IH=1: [64,128) [256,320)
//   IH=2: [128,192) [320,384)          (union = [0,400), disjoint)
// ---------------------------------------------------------------------------
template<int IH>
__device__ __forceinline__ void phase2(
    int b, int a, bool diag, int t,
    const float (*yc)[28], const float* su, const float* sv,
    const float* sp, const float* sq_, const float* sLamA,
    const float* __restrict__ inv_K, const float* __restrict__ ws,
    float& accS_out, float& accT_out)
{
    const int tx = t & 15, ty = t >> 4;
    float accS = 0.f, accT = 0.f;
    for (int i0 = IH*64; i0 < Ndim; i0 += 192) {
        const int ia = i0 + ty;
        const int ib = i0 + 32 + ty;
        const bool va = (ia < Ndim), vb = (ib < Ndim);
        const int sa = va ? ia : 0, sb = vb ? ib : 0;
        float zra[Ddim], zrb[Ddim];
        #pragma unroll
        for (int d = 0; d < Ddim; d++) {
            zra[d] = ws[WS_INP + (b*Ndim + sa)*Ddim + d] * sLamA[d];
            zrb[d] = ws[WS_INP + (b*Ndim + sb)*Ddim + d] * sLamA[d];
        }
        const float ua = va ? su[ia] : 0.f;
        const float ub = vb ? su[ib] : 0.f;
        const float pa = (va && diag) ? sp[ia] : 0.f;
        const float pb = (vb && diag) ? sp[ib] : 0.f;
        const float* kra = &inv_K[((size_t)a*Ndim + sa)*Ndim];
        const float* krb = &inv_K[((size_t)a*Ndim + sb)*Ndim];
        for (int j0 = 0; j0 < Ndim; j0 += 16) {
            const int j = j0 + tx;
            float da = 0.f, db = 0.f;
            #pragma unroll
            for (int d = 0; d < Ddim; d++) {
                const float y = yc[j][d];
                da = fmaf(zra[d], y, da);
                db = fmaf(zrb[d], y, db);
            }
            const float ea = __expf(2.f*da);
            const float eb = __expf(2.f*db);
            const float svj = sv[j];
            accS = fmaf(ua*svj, ea, accS);
            accS = fmaf(ub*svj, eb, accS);
            if (diag) {
                const float sqj = sq_[j];
                accT = fmaf(pa*sqj*kra[j], ea, accT);
                accT = fmaf(pb*sqj*krb[j], eb, accT);
            }
        }
    }
    accS_out = accS;
    accT_out = accT;
}

// ---------------------------------------------------------------------------
// Kernel B: per (b, pair a<=c, IH of 3): full yc tile, fused 2-chain phase 1,
// then phase2<IH> (2 i-rows/thread). Partial sums merged via global atomicAdd.
// ---------------------------------------------------------------------------
__global__ __launch_bounds__(512) void main_kernel(
    const float* __restrict__ lengthscales, const float* __restrict__ beta,
    const float* __restrict__ inv_K, float* __restrict__ ws)
{
    const int bid = blockIdx.x;
    const int b = bid / (NPAIR*3);
    const int rem = bid % (NPAIR*3);
    const int pair = rem / 3;
    const int ih = rem % 3;
    // decode upper-triangular pair (a <= c)
    int p = pair, a = 0;
    while (p >= Edim - a) { p -= Edim - a; a++; }
    const int c = a + p;
    const int t = threadIdx.x;
    const int NT = 512;
    const bool diag = (a == c);
    const int cidx = (b*Edim + a)*Edim + c;   // canonical slot

    __shared__ float sS[Ddim][Ddim];
    __shared__ float sQ2[Ddim][Ddim];
    __shared__ float aug[Ddim][2*Ddim];
    __shared__ float fac[Ddim];
    __shared__ float sLamA[Ddim], sLamC[Ddim];
    __shared__ float yc[Ndim][28];          // padded: stride 112B, 16B-aligned rows
    __shared__ float su[Ndim], sv[Ndim], sp[Ndim], sq_[Ndim];
    __shared__ float slogdet, redS, redT;

    if (t < Ddim) {
        float La = lengthscales[a*Ddim + t];
        float Lc = lengthscales[c*Ddim + t];
        sLamA[t] = 1.f/(La*La);
        sLamC[t] = 1.f/(Lc*Lc);
    }
    if (t == 0) { slogdet = 0.f; redS = 0.f; redT = 0.f; }
    for (int idx = t; idx < Ddim*Ddim; idx += NT)
        sS[idx/Ddim][idx%Ddim] = ws[WS_S + b*Ddim*Ddim + idx];
    __syncthreads();

    // R = S*diag(LamA+LamC) + I, RHS = S
    for (int idx = t; idx < Ddim*2*Ddim; idx += NT) {
        int i = idx/(2*Ddim), j = idx%(2*Ddim);
        float v;
        if (j < Ddim) v = sS[i][j]*(sLamA[j]+sLamC[j]) + ((i==j) ? 1.f : 0.f);
        else          v = sS[i][j-Ddim];
        aug[i][j] = v;
    }
    __syncthreads();
    for (int k = 0; k < Ddim; k++) {
        float piv = aug[k][k];
        __syncthreads();
        float ipv = 1.f/piv;
        if (t < 2*Ddim) aug[k][t] *= ipv;
        if (t < Ddim) fac[t] = aug[t][k];
        if (t == 0) slogdet += logf(fabsf(piv));
        __syncthreads();
        for (int idx = t; idx < Ddim*2*Ddim; idx += NT) {
            int i = idx/(2*Ddim), j = idx%(2*Ddim);
            if (i != k) aug[i][j] -= fac[i]*aug[k][j];
        }
        __syncthreads();
    }
    for (int idx = t; idx < Ddim*Ddim; idx += NT) {
        int i = idx/Ddim, j = idx%Ddim;
        sQ2[i][j] = 0.5f*aug[i][Ddim + j];
    }
    if (t == 0 && ih == 0) ws[WS_SCALE + cidx] = __expf(-0.5f*slogdet);
    __syncthreads();

    // phase 1: per training point n (all 400): Yc = Q2 z_c, Xs, X2s, u, v, p, q
    if (t < Ndim) {
        int n = t;
        float zav[Ddim], zcv[Ddim];
        #pragma unroll
        for (int d = 0; d < Ddim; d++) {
            float x = ws[WS_INP + (b*Ndim + n)*Ddim + d];
            zav[d] = x * sLamA[d];
            zcv[d] = x * sLamC[d];
        }
        float xs = 0.f, x2s = 0.f;
        #pragma unroll
        for (int i = 0; i < Ddim; i++) {
            float ya = 0.f, ycv = 0.f;
            #pragma unroll
            for (int j = 0; j < Ddim; j++) {
                ya  = fmaf(sQ2[i][j], zav[j], ya);
                ycv = fmaf(sQ2[i][j], zcv[j], ycv);
            }
            xs  = fmaf(zav[i], ya, xs);
            x2s = fmaf(zcv[i], ycv, x2s);
            yc[n][i] = ycv;
        }
        float lka = ws[WS_LOGK + (b*Edim + a)*Ndim + n];
        float lkc = ws[WS_LOGK + (b*Edim + c)*Ndim + n];
        float pa = __expf(lka + xs);
        float qc = __expf(lkc + x2s);
        sp[n] = pa; sq_[n] = qc;
        su[n] = beta[a*Ndim + n]*pa;
        sv[n] = beta[c*Ndim + n]*qc;
    }
    __syncthreads();

    // phase 2: constant-bound instantiation selected by block-uniform ih
    float accS, accT;
    if (ih == 0)      phase2<0>(b, a, diag, t, yc, su, sv, sp, sq_, sLamA, inv_K, ws, accS, accT);
    else if (ih == 1) phase2<1>(b, a, diag, t, yc, su, sv, sp, sq_, sLamA, inv_K, ws, accS, accT);
    else              phase2<2>(b, a, diag, t, yc, su, sv, sp, sq_, sLamA, inv_K, ws, accS, accT);

    atomicAdd(&redS, accS);
    if (diag) atomicAdd(&redT, accT);
    __syncthreads();
    if (t == 0) {
        atomicAdd(&ws[WS_SBLB + cidx], redS);
        if (diag) atomicAdd(&ws[WS_TR + b*Edim + a], redT);
    }
}

// ---------------------------------------------------------------------------
// Kernel C: assemble next_mean / next_var (SBLB/SCALE read from canonical slot)
// ---------------------------------------------------------------------------
__global__ __launch_bounds__(256) void final_kernel(
    const float* __restrict__ m_x, const float* __restrict__ s_x,
    const float* __restrict__ variances, const float* __restrict__ ws,
    float* __restrict__ out)
{
    const int b = blockIdx.x;
    const int t = threadIdx.x;
    if (t < Edim) out[b*Edim + t] = m_x[b*Edim + t] + ws[WS_PM + b*Edim + t];
    const int i = t >> 4, j = t & 15;
    const int lo = (i < j) ? i : j;
    const int hi = (i < j) ? j : i;
    float pmi = ws[WS_PM + b*Edim + i], pmj = ws[WS_PM + b*Edim + j];
    float cxij = 0.f, cxji = 0.f;
    #pragma unroll
    for (int d = 0; d < Ddim; d++) {
        cxij += ws[WS_S + b*Ddim*Ddim + i*Ddim + d]*ws[WS_V + (b*Ddim + d)*Edim + j];
        cxji += ws[WS_S + b*Ddim*Ddim + j*Ddim + d]*ws[WS_V + (b*Ddim + d)*Edim + i];
    }
    float sb  = ws[WS_SBLB + (b*Edim + lo)*Edim + hi];
    float scl = ws[WS_SCALE + (b*Edim + lo)*Edim + hi];
    float sd = sb;
    if (i == j) sd -= ws[WS_TR + b*Edim + i];
    sd = sd*scl + ((i==j) ? variances[i] : 0.f) - pmi*pmj;
    out[Bdim*Edim + (b*Edim + i)*Edim + j] = s_x[(b*Edim + i)*Edim + j] + sd + cxij + cxji;
}

extern "C" void kernel_launch(void* const* d_in, const int* in_sizes, int n_in,
                              void* d_out, int out_size, void* d_ws, size_t ws_size,
                              hipStream_t stream) {
    const float* m_x     = (const float*)d_in[0];
    const float* s_x     = (const float*)d_in[1];
    const float* m_u     = (const float*)d_in[2];
    const float* s_u     = (const float*)d_in[3];
    const float* c_xu    = (const float*)d_in[4];
    const float* X_train = (const float*)d_in[5];
    const float* ls      = (const float*)d_in[6];
    const float* var     = (const float*)d_in[7];
    // d_in[8] = noises, unused in moment matching
    const float* inv_K   = (const float*)d_in[9];
    const float* beta    = (const float*)d_in[10];
    float* ws  = (float*)d_ws;
    float* out = (float*)d_out;

    // zero the atomically-accumulated slots (SBLB + TR are contiguous)
    hipMemsetAsync(ws + WS_SBLB, 0, (Bdim*Edim*Edim + Bdim*Edim)*sizeof(float), stream);

    hipLaunchKernelGGL(prep_kernel, dim3(Bdim*Edim), dim3(256), 0, stream,
        m_x, s_x, m_u, s_u, c_xu, X_train, ls, var, beta, ws);
    hipLaunchKernelGGL(main_kernel, dim3(Bdim*NPAIR*3), dim3(512), 0, stream,
        ls, beta, inv_K, ws);
    hipLaunchKernelGGL(final_kernel, dim3(Bdim), dim3(256), 0, stream,
        m_x, s_x, var, ws, out);
}